// Round 1
// baseline (379.975 us; speedup 1.0000x reference)
//
#include <hip/hip_runtime.h>
#include <hip/hip_bf16.h>

#define BD 8192
#define DD 1024

typedef __attribute__((ext_vector_type(8))) short short8;
typedef __attribute__((ext_vector_type(4))) float floatx4;

__device__ inline float bf2f(unsigned short u) {
    union { unsigned int u; float f; } un;
    un.u = ((unsigned int)u) << 16;
    return un.f;
}
__device__ inline unsigned short f2bf(float f) {
    union { float f; unsigned int u; } un;
    un.f = f;
    unsigned int u = un.u;
    u += 0x7FFF + ((u >> 16) & 1);   // round-to-nearest-even
    return (unsigned short)(u >> 16);
}

// One block per row: compute L2 norm, write normalized bf16, optional entropy accum.
template <bool ENT>
__global__ __launch_bounds__(256) void norm_rows(const float* __restrict__ x,
                                                 unsigned short* __restrict__ xb,
                                                 float* __restrict__ ent_acc) {
    __shared__ float s1[4];
    __shared__ float s2[4];
    int row = blockIdx.x;
    const float4* xr = (const float4*)(x + (size_t)row * DD);
    float4 v = xr[threadIdx.x];
    float ss = v.x * v.x + v.y * v.y + v.z * v.z + v.w * v.w;
#pragma unroll
    for (int off = 1; off < 64; off <<= 1) ss += __shfl_xor(ss, off);
    int wid = threadIdx.x >> 6, lane = threadIdx.x & 63;
    if (lane == 0) s1[wid] = ss;
    __syncthreads();
    float tot = s1[0] + s1[1] + s1[2] + s1[3];
    float inv = 1.0f / fmaxf(sqrtf(tot), 1e-12f);
    float a = v.x * inv, b = v.y * inv, c = v.z * inv, d = v.w * inv;
    ushort4 o;
    o.x = f2bf(a); o.y = f2bf(b); o.z = f2bf(c); o.w = f2bf(d);
    ((ushort4*)(xb + (size_t)row * DD))[threadIdx.x] = o;
    if (ENT) {
        float e = a * __logf(a + 1e-8f) + b * __logf(b + 1e-8f) +
                  c * __logf(c + 1e-8f) + d * __logf(d + 1e-8f);
#pragma unroll
        for (int off = 1; off < 64; off <<= 1) e += __shfl_xor(e, off);
        if (lane == 0) s2[wid] = e;
        __syncthreads();
        if (threadIdx.x == 0) atomicAdd(ent_acc, s2[0] + s2[1] + s2[2] + s2[3]);
    }
}

// T = AN @ link^T (both row-major, K contiguous), fused epilogue:
// cos_partial[b] += sum_i T[b][i] * rn[b][i]
// Wave computes a 64x64 tile (4x4 of 16x16x32 MFMA frags); block = 4 waves = 128x128.
__global__ __launch_bounds__(256) void gemm_cos(const unsigned short* __restrict__ anb,
                                                const unsigned short* __restrict__ linkb,
                                                const unsigned short* __restrict__ rnb,
                                                float* __restrict__ cos_partial) {
    int wid = threadIdx.x >> 6;
    int lane = threadIdx.x & 63;
    int wm = wid >> 1, wn = wid & 1;
    int b0 = (blockIdx.x >> 3) * 128 + wm * 64;   // batch rows
    int i0 = (blockIdx.x & 7) * 128 + wn * 64;    // link rows (output cols)
    int r = lane & 15;
    int kg = lane >> 4;

    const unsigned short* ap = anb + (size_t)(b0 + r) * DD + kg * 8;
    const unsigned short* bp = linkb + (size_t)(i0 + r) * DD + kg * 8;

    floatx4 acc[4][4];
#pragma unroll
    for (int m = 0; m < 4; ++m)
#pragma unroll
        for (int n = 0; n < 4; ++n) acc[m][n] = (floatx4)0.0f;

    for (int k0 = 0; k0 < DD; k0 += 32) {
        short8 af[4], bfv[4];
#pragma unroll
        for (int m = 0; m < 4; ++m)
            af[m] = *(const short8*)(ap + (size_t)m * 16 * DD + k0);
#pragma unroll
        for (int n = 0; n < 4; ++n)
            bfv[n] = *(const short8*)(bp + (size_t)n * 16 * DD + k0);
#pragma unroll
        for (int m = 0; m < 4; ++m)
#pragma unroll
            for (int n = 0; n < 4; ++n)
                acc[m][n] = __builtin_amdgcn_mfma_f32_16x16x32_bf16(af[m], bfv[n], acc[m][n], 0, 0, 0);
    }

    // Epilogue: acc[m][n][rr] = T[b0 + m*16 + kg*4 + rr][i0 + n*16 + r]
#pragma unroll
    for (int m = 0; m < 4; ++m) {
#pragma unroll
        for (int rr = 0; rr < 4; ++rr) {
            int bb = b0 + m * 16 + kg * 4 + rr;
            float p = 0.f;
#pragma unroll
            for (int n = 0; n < 4; ++n) {
                int ii = i0 + n * 16 + r;
                p += acc[m][n][rr] * bf2f(rnb[(size_t)bb * DD + ii]);
            }
#pragma unroll
            for (int off = 1; off < 16; off <<= 1) p += __shfl_xor(p, off);
            if (r == 0) atomicAdd(&cos_partial[bb], p);
        }
    }
}

__global__ __launch_bounds__(256) void finalize(const float* __restrict__ cos_partial,
                                                const float* __restrict__ ent_acc,
                                                const float* __restrict__ temp,
                                                float* __restrict__ out) {
    __shared__ float sb[4];
    float s = 0.f;
    for (int i = threadIdx.x; i < BD; i += 256) s += cos_partial[i];
#pragma unroll
    for (int off = 1; off < 64; off <<= 1) s += __shfl_xor(s, off);
    int wid = threadIdx.x >> 6, lane = threadIdx.x & 63;
    if (lane == 0) sb[wid] = s;
    __syncthreads();
    if (threadIdx.x == 0) {
        float total = sb[0] + sb[1] + sb[2] + sb[3];
        float ent_rna = -ent_acc[0] / (float)BD;
        float ent_atac = -ent_acc[1] / (float)BD;
        float avg = 0.5f * (ent_rna + ent_atac);
        float t = temp[0];
        float sg = 1.0f / (1.0f + __expf(-t));
        float scale = sg * 0.1f + (1.0f - sg) * avg;
        float tau = fminf(fmaxf(scale, 0.01f), 1.0f);
        out[0] = -(total / (float)BD) / tau;
    }
}

extern "C" void kernel_launch(void* const* d_in, const int* in_sizes, int n_in,
                              void* d_out, int out_size, void* d_ws, size_t ws_size,
                              hipStream_t stream) {
    const float* z_rna = (const float*)d_in[0];
    const float* z_atac = (const float*)d_in[1];
    const float* link = (const float*)d_in[2];
    const float* temp = (const float*)d_in[3];
    float* out = (float*)d_out;

    char* ws = (char*)d_ws;
    float* cos_partial = (float*)ws;                                   // 8192 f32
    float* ent_acc = (float*)(ws + 32768);                             // 2 f32
    unsigned short* linkb = (unsigned short*)(ws + 33024);             // 2 MB
    unsigned short* rnb = (unsigned short*)(ws + 33024 + 2097152);     // 16 MB
    unsigned short* anb = (unsigned short*)(ws + 33024 + 2097152 + 16777216);  // 16 MB

    hipMemsetAsync(d_ws, 0, 33024, stream);
    norm_rows<false><<<DD, 256, 0, stream>>>(link, linkb, nullptr);
    norm_rows<true><<<BD, 256, 0, stream>>>(z_rna, rnb, ent_acc);
    norm_rows<true><<<BD, 256, 0, stream>>>(z_atac, anb, ent_acc + 1);
    gemm_cos<<<512, 256, 0, stream>>>(anb, linkb, rnb, cos_partial);
    finalize<<<1, 256, 0, stream>>>(cos_partial, ent_acc, temp, out);
}

// Round 2
// 149.869 us; speedup vs baseline: 2.5354x; 2.5354x over previous
//
#include <hip/hip_runtime.h>
#include <hip/hip_bf16.h>

#define BD 8192
#define DD 1024
#define BM 128
#define BN 128
#define BKK 64

typedef __attribute__((ext_vector_type(8))) short short8;
typedef __attribute__((ext_vector_type(4))) float floatx4;

__device__ inline float bf2f(unsigned short u) {
    union { unsigned int u; float f; } un;
    un.u = ((unsigned int)u) << 16;
    return un.f;
}
__device__ inline unsigned short f2bf(float f) {
    union { float f; unsigned int u; } un;
    un.f = f;
    unsigned int u = un.u;
    u += 0x7FFF + ((u >> 16) & 1);   // round-to-nearest-even
    return (unsigned short)(u >> 16);
}

__device__ inline void gld_lds16(const void* g, void* l) {
    __builtin_amdgcn_global_load_lds(
        (const __attribute__((address_space(1))) unsigned int*)g,
        (__attribute__((address_space(3))) unsigned int*)l, 16, 0, 0);
}

// Wave-per-row L2 normalize: 64 lanes x 4 float4 = 1024 floats = one row.
// No barriers in the loop, no atomics; entropy partial per block into ent_part[].
template <bool ENT>
__global__ __launch_bounds__(256) void norm_wave(const float* __restrict__ x,
                                                 unsigned short* __restrict__ xb,
                                                 float* __restrict__ ent_part,
                                                 int nrows) {
    int lane = threadIdx.x & 63;
    int wid = threadIdx.x >> 6;
    int gw = blockIdx.x * 4 + wid;
    int nw = gridDim.x * 4;
    float epart = 0.f;
    for (int row = gw; row < nrows; row += nw) {
        const float4* xr = (const float4*)(x + (size_t)row * DD);
        float4 v0 = xr[lane];
        float4 v1 = xr[lane + 64];
        float4 v2 = xr[lane + 128];
        float4 v3 = xr[lane + 192];
        float ss = v0.x*v0.x + v0.y*v0.y + v0.z*v0.z + v0.w*v0.w
                 + v1.x*v1.x + v1.y*v1.y + v1.z*v1.z + v1.w*v1.w
                 + v2.x*v2.x + v2.y*v2.y + v2.z*v2.z + v2.w*v2.w
                 + v3.x*v3.x + v3.y*v3.y + v3.z*v3.z + v3.w*v3.w;
#pragma unroll
        for (int off = 1; off < 64; off <<= 1) ss += __shfl_xor(ss, off);
        float inv = 1.0f / fmaxf(sqrtf(ss), 1e-12f);
        ushort4* orow = (ushort4*)(xb + (size_t)row * DD);
        float4 vv[4] = {v0, v1, v2, v3};
#pragma unroll
        for (int i = 0; i < 4; ++i) {
            float a = vv[i].x * inv, b = vv[i].y * inv, c = vv[i].z * inv, d = vv[i].w * inv;
            ushort4 o;
            o.x = f2bf(a); o.y = f2bf(b); o.z = f2bf(c); o.w = f2bf(d);
            orow[lane + 64 * i] = o;
            if (ENT) {
                epart += a * __logf(a + 1e-8f) + b * __logf(b + 1e-8f)
                       + c * __logf(c + 1e-8f) + d * __logf(d + 1e-8f);
            }
        }
    }
    if (ENT) {
#pragma unroll
        for (int off = 1; off < 64; off <<= 1) epart += __shfl_xor(epart, off);
        __shared__ float sw[4];
        if (lane == 0) sw[wid] = epart;
        __syncthreads();
        if (threadIdx.x == 0) ent_part[blockIdx.x] = sw[0] + sw[1] + sw[2] + sw[3];
    }
}

// T = AN @ link^T, fused cos epilogue. m97 structure: 128x128 tile, BK=64,
// global_load_lds width-16 staging into XOR-swizzled LDS (pre-swizzled global
// source + swizzled ds_read: byte ^= (row&7)<<4), 4x4 frags/wave, 2 barriers/K-step.
__global__ __launch_bounds__(256) void gemm_cos(const unsigned short* __restrict__ anb,
                                                const unsigned short* __restrict__ linkb,
                                                const unsigned short* __restrict__ rnb,
                                                float* __restrict__ cos_partial) {
    __shared__ unsigned short As[BM * BKK];
    __shared__ unsigned short Bs[BN * BKK];

    // XCD-bijective mapping: all 8 i-tiles of a b-tile on one XCD (A read once/XCD).
    int bid = blockIdx.x;          // 512 blocks
    int j = bid >> 3;              // 0..63
    int btile = (bid & 7) * 8 + (j & 7);
    int itile = j >> 3;            // 0..7
    int b0 = btile * BM;
    int i0 = itile * BN;

    int tid = threadIdx.x;
    int wid = tid >> 6, lane = tid & 63;
    int wm = wid >> 1, wn = wid & 1;
    int r = lane & 15, kg = lane >> 4;

    // Staging: chunk c stages LDS bytes [c*4096 + tid*16). row = c*32 + (tid>>3),
    // lds col byte = (tid&7)*16; global col byte = lds ^ ((row&7)<<4)  (row&7 == srow&7).
    int srow = tid >> 3;                    // 0..31
    int scb = (tid & 7) * 16;
    int scb_src = scb ^ ((srow & 7) << 4);

    const char* agbase = (const char*)anb + ((size_t)(b0 + srow) * DD) * 2 + scb_src;
    const char* bgbase = (const char*)linkb + ((size_t)(i0 + srow) * DD) * 2 + scb_src;
    unsigned short* al = As + srow * BKK + scb / 2;
    unsigned short* bl = Bs + srow * BKK + scb / 2;

    floatx4 acc[4][4];
#pragma unroll
    for (int m = 0; m < 4; ++m)
#pragma unroll
        for (int n = 0; n < 4; ++n) acc[m][n] = (floatx4)0.0f;

    // prologue stage k0=0
#pragma unroll
    for (int c = 0; c < 4; ++c) {
        gld_lds16(agbase + (size_t)c * 32 * DD * 2, al + c * 2048);
        gld_lds16(bgbase + (size_t)c * 32 * DD * 2, bl + c * 2048);
    }

    for (int k0 = 0; k0 < DD; k0 += BKK) {
        __syncthreads();   // drains vmcnt before compute (compiler-inserted waitcnt)
#pragma unroll
        for (int kk = 0; kk < 2; ++kk) {
            short8 a_[4], b_[4];
#pragma unroll
            for (int m = 0; m < 4; ++m) {
                int row = wm * 64 + m * 16 + r;
                int cb = (kg * 16 + kk * 64) ^ ((row & 7) << 4);
                a_[m] = *(const short8*)((const char*)As + row * 128 + cb);
            }
#pragma unroll
            for (int n = 0; n < 4; ++n) {
                int row = wn * 64 + n * 16 + r;
                int cb = (kg * 16 + kk * 64) ^ ((row & 7) << 4);
                b_[n] = *(const short8*)((const char*)Bs + row * 128 + cb);
            }
#pragma unroll
            for (int m = 0; m < 4; ++m)
#pragma unroll
                for (int n = 0; n < 4; ++n)
                    acc[m][n] = __builtin_amdgcn_mfma_f32_16x16x32_bf16(a_[m], b_[n], acc[m][n], 0, 0, 0);
        }
        __syncthreads();   // all reads done before overwrite
        if (k0 + BKK < DD) {
            size_t kb = (size_t)(k0 + BKK) * 2;
#pragma unroll
            for (int c = 0; c < 4; ++c) {
                gld_lds16(agbase + (size_t)c * 32 * DD * 2 + kb, al + c * 2048);
                gld_lds16(bgbase + (size_t)c * 32 * DD * 2 + kb, bl + c * 2048);
            }
        }
    }

    // Epilogue: acc[m][n][rr] = T[b0w + m*16 + kg*4 + rr][i0w + n*16 + r]
    int b0w = b0 + wm * 64, i0w = i0 + wn * 64;
#pragma unroll
    for (int m = 0; m < 4; ++m) {
#pragma unroll
        for (int rr = 0; rr < 4; ++rr) {
            int bb = b0w + m * 16 + kg * 4 + rr;
            float p = 0.f;
#pragma unroll
            for (int n = 0; n < 4; ++n) {
                int ii = i0w + n * 16 + r;
                p += acc[m][n][rr] * bf2f(rnb[(size_t)bb * DD + ii]);
            }
#pragma unroll
            for (int off = 1; off < 16; off <<= 1) p += __shfl_xor(p, off);
            if (r == 0) atomicAdd(&cos_partial[bb], p);
        }
    }
}

__global__ __launch_bounds__(256) void finalize(const float* __restrict__ cos_partial,
                                                const float* __restrict__ er,
                                                const float* __restrict__ ea,
                                                const float* __restrict__ temp,
                                                float* __restrict__ out) {
    __shared__ float sb[4][3];
    float s = 0.f, se = 0.f, sa = 0.f;
    for (int i = threadIdx.x; i < BD; i += 256) s += cos_partial[i];
    for (int i = threadIdx.x; i < 1024; i += 256) { se += er[i]; sa += ea[i]; }
#pragma unroll
    for (int off = 1; off < 64; off <<= 1) {
        s += __shfl_xor(s, off);
        se += __shfl_xor(se, off);
        sa += __shfl_xor(sa, off);
    }
    int wid = threadIdx.x >> 6, lane = threadIdx.x & 63;
    if (lane == 0) { sb[wid][0] = s; sb[wid][1] = se; sb[wid][2] = sa; }
    __syncthreads();
    if (threadIdx.x == 0) {
        float total = sb[0][0] + sb[1][0] + sb[2][0] + sb[3][0];
        float ser = sb[0][1] + sb[1][1] + sb[2][1] + sb[3][1];
        float sea = sb[0][2] + sb[1][2] + sb[2][2] + sb[3][2];
        float ent_rna = -ser / (float)BD;
        float ent_atac = -sea / (float)BD;
        float avg = 0.5f * (ent_rna + ent_atac);
        float t = temp[0];
        float sg = 1.0f / (1.0f + __expf(-t));
        float scale = sg * 0.1f + (1.0f - sg) * avg;
        float tau = fminf(fmaxf(scale, 0.01f), 1.0f);
        out[0] = -(total / (float)BD) / tau;
    }
}

extern "C" void kernel_launch(void* const* d_in, const int* in_sizes, int n_in,
                              void* d_out, int out_size, void* d_ws, size_t ws_size,
                              hipStream_t stream) {
    const float* z_rna = (const float*)d_in[0];
    const float* z_atac = (const float*)d_in[1];
    const float* link = (const float*)d_in[2];
    const float* temp = (const float*)d_in[3];
    float* out = (float*)d_out;

    char* ws = (char*)d_ws;
    float* cos_partial = (float*)ws;                                   // 8192 f32 = 32KB
    float* er_part = (float*)(ws + 32768);                             // 1024 f32
    float* ea_part = (float*)(ws + 36864);                             // 1024 f32
    unsigned short* linkb = (unsigned short*)(ws + 40960);             // 2 MB
    unsigned short* rnb = (unsigned short*)(ws + 40960 + 2097152);     // 16 MB
    unsigned short* anb = (unsigned short*)(ws + 40960 + 2097152 + 16777216); // 16 MB

    hipMemsetAsync(d_ws, 0, 40960, stream);
    norm_wave<false><<<256, 256, 0, stream>>>(link, linkb, nullptr, DD);
    norm_wave<true><<<1024, 256, 0, stream>>>(z_rna, rnb, er_part, BD);
    norm_wave<true><<<1024, 256, 0, stream>>>(z_atac, anb, ea_part, BD);
    gemm_cos<<<512, 256, 0, stream>>>(anb, linkb, rnb, cos_partial);
    finalize<<<1, 256, 0, stream>>>(cos_partial, er_part, ea_part, temp, out);
}

// Round 3
// 129.387 us; speedup vs baseline: 2.9367x; 1.1583x over previous
//
#include <hip/hip_runtime.h>
#include <hip/hip_bf16.h>

#define BD 8192
#define DD 1024
#define BM 128
#define BN 128
#define BKK 64

typedef __attribute__((ext_vector_type(8))) short short8;
typedef __attribute__((ext_vector_type(4))) float floatx4;

__device__ inline float bf2f(unsigned short u) {
    union { unsigned int u; float f; } un;
    un.u = ((unsigned int)u) << 16;
    return un.f;
}
__device__ inline unsigned short f2bf(float f) {
    union { float f; unsigned int u; } un;
    un.f = f;
    unsigned int u = un.u;
    u += 0x7FFF + ((u >> 16) & 1);   // round-to-nearest-even
    return (unsigned short)(u >> 16);
}

__device__ inline void gld_lds16(const void* g, void* l) {
    __builtin_amdgcn_global_load_lds(
        (const __attribute__((address_space(1))) unsigned int*)g,
        (__attribute__((address_space(3))) unsigned int*)l, 16, 0, 0);
}

// All three normalizations in one launch. Wave-per-row (64 lanes x 4 float4 = 1024 f32).
// blocks [0,2048): z_rna -> rnb (+entropy er), [2048,4096): z_atac -> anb (+ea),
// [4096,4352): link -> linkb (no entropy).
__global__ __launch_bounds__(256) void norm_all(const float* __restrict__ rna,
                                                const float* __restrict__ atac,
                                                const float* __restrict__ link,
                                                unsigned short* __restrict__ rnb,
                                                unsigned short* __restrict__ anb,
                                                unsigned short* __restrict__ linkb,
                                                float* __restrict__ er,
                                                float* __restrict__ ea) {
    int bid = blockIdx.x;
    int wid = threadIdx.x >> 6, lane = threadIdx.x & 63;
    const float* x;
    unsigned short* xb;
    float* ep;
    int row;
    bool ent = true;
    if (bid < 2048)      { x = rna;  xb = rnb;   ep = er + bid;          row = bid * 4 + wid; }
    else if (bid < 4096) { x = atac; xb = anb;   ep = ea + (bid - 2048); row = (bid - 2048) * 4 + wid; }
    else                 { x = link; xb = linkb; ep = nullptr;           row = (bid - 4096) * 4 + wid; ent = false; }

    const float4* xr = (const float4*)(x + (size_t)row * DD);
    float4 v0 = xr[lane];
    float4 v1 = xr[lane + 64];
    float4 v2 = xr[lane + 128];
    float4 v3 = xr[lane + 192];
    float ss = v0.x*v0.x + v0.y*v0.y + v0.z*v0.z + v0.w*v0.w
             + v1.x*v1.x + v1.y*v1.y + v1.z*v1.z + v1.w*v1.w
             + v2.x*v2.x + v2.y*v2.y + v2.z*v2.z + v2.w*v2.w
             + v3.x*v3.x + v3.y*v3.y + v3.z*v3.z + v3.w*v3.w;
#pragma unroll
    for (int off = 1; off < 64; off <<= 1) ss += __shfl_xor(ss, off);
    float inv = 1.0f / fmaxf(sqrtf(ss), 1e-12f);
    ushort4* orow = (ushort4*)(xb + (size_t)row * DD);
    float4 vv[4] = {v0, v1, v2, v3};
    float epart = 0.f;
#pragma unroll
    for (int i = 0; i < 4; ++i) {
        float a = vv[i].x * inv, b = vv[i].y * inv, c = vv[i].z * inv, d = vv[i].w * inv;
        ushort4 o;
        o.x = f2bf(a); o.y = f2bf(b); o.z = f2bf(c); o.w = f2bf(d);
        orow[lane + 64 * i] = o;
        if (ent) {
            epart += a * __logf(a + 1e-8f) + b * __logf(b + 1e-8f)
                   + c * __logf(c + 1e-8f) + d * __logf(d + 1e-8f);
        }
    }
    if (ent) {
#pragma unroll
        for (int off = 1; off < 64; off <<= 1) epart += __shfl_xor(epart, off);
        __shared__ float sw[4];
        if (lane == 0) sw[wid] = epart;
        __syncthreads();
        if (threadIdx.x == 0) ep[0] = sw[0] + sw[1] + sw[2] + sw[3];
    }
}

// Split-K GEMM, sum-only fused epilogue.
// Each block: partial T (128x128 tile of AN@link^T over K-half), dotted with rn tile,
// one f32 written to gpart[blockIdx.x]. No atomics, no per-row output.
__global__ __launch_bounds__(256) void gemm_cos(const unsigned short* __restrict__ anb,
                                                const unsigned short* __restrict__ linkb,
                                                const unsigned short* __restrict__ rnb,
                                                float* __restrict__ gpart) {
    __shared__ unsigned short As[BM * BKK];
    __shared__ unsigned short Bs[BN * BKK];

    // 1024 blocks = 64 btiles x 8 itiles x 2 ksplits; bid&7 = XCD.
    // Per XCD: btiles xcd*8..xcd*8+7, all itiles/ksplits -> AN chunk (2MB) + link (2MB) fit L2.
    int bid = blockIdx.x;
    int j = bid >> 3;                      // 0..127
    int btile = (bid & 7) * 8 + (j & 7);   // 0..63
    int itile = (j >> 3) & 7;              // 0..7
    int ks = j >> 6;                       // 0..1
    int b0 = btile * BM;
    int i0 = itile * BN;
    int kbase = ks * 512;

    int tid = threadIdx.x;
    int wid = tid >> 6, lane = tid & 63;
    int wm = wid >> 1, wn = wid & 1;
    int r = lane & 15, kg = lane >> 4;

    // Staging: LDS byte = tid*16 (linear); row = tid>>3, col byte = (tid&7)*16.
    // Global source column pre-swizzled: src_cb = cb ^ ((row&7)<<4)  (rule 21).
    int srow = tid >> 3;
    int scb = (tid & 7) * 16;
    int scb_src = scb ^ ((srow & 7) << 4);

    const char* agbase = (const char*)anb + ((size_t)(b0 + srow) * DD + kbase) * 2 + scb_src;
    const char* bgbase = (const char*)linkb + ((size_t)(i0 + srow) * DD + kbase) * 2 + scb_src;
    unsigned short* al = As + srow * BKK + scb / 2;
    unsigned short* bl = Bs + srow * BKK + scb / 2;

    floatx4 acc[4][4];
#pragma unroll
    for (int m = 0; m < 4; ++m)
#pragma unroll
        for (int n = 0; n < 4; ++n) acc[m][n] = (floatx4)0.0f;

    // prologue: stage first K-step
#pragma unroll
    for (int c = 0; c < 4; ++c) {
        gld_lds16(agbase + (size_t)c * 32 * DD * 2, al + c * 2048);
        gld_lds16(bgbase + (size_t)c * 32 * DD * 2, bl + c * 2048);
    }

    for (int step = 0; step < 8; ++step) {
        __syncthreads();
#pragma unroll
        for (int kk = 0; kk < 2; ++kk) {
            short8 a_[4], b_[4];
#pragma unroll
            for (int m = 0; m < 4; ++m) {
                int row = wm * 64 + m * 16 + r;
                int cb = (kg * 16 + kk * 64) ^ ((row & 7) << 4);
                a_[m] = *(const short8*)((const char*)As + row * 128 + cb);
            }
#pragma unroll
            for (int n = 0; n < 4; ++n) {
                int row = wn * 64 + n * 16 + r;
                int cb = (kg * 16 + kk * 64) ^ ((row & 7) << 4);
                b_[n] = *(const short8*)((const char*)Bs + row * 128 + cb);
            }
#pragma unroll
            for (int m = 0; m < 4; ++m)
#pragma unroll
                for (int n = 0; n < 4; ++n)
                    acc[m][n] = __builtin_amdgcn_mfma_f32_16x16x32_bf16(a_[m], b_[n], acc[m][n], 0, 0, 0);
        }
        __syncthreads();
        if (step < 7) {
            size_t kb = (size_t)(step + 1) * BKK * 2;
#pragma unroll
            for (int c = 0; c < 4; ++c) {
                gld_lds16(agbase + (size_t)c * 32 * DD * 2 + kb, al + c * 2048);
                gld_lds16(bgbase + (size_t)c * 32 * DD * 2 + kb, bl + c * 2048);
            }
        }
    }

    // Epilogue: s = sum_{m,n,rr} acc[m][n][rr] * rn[bb][ii]; block-reduce to one float.
    int b0w = b0 + wm * 64, i0w = i0 + wn * 64;
    float s = 0.f;
#pragma unroll
    for (int m = 0; m < 4; ++m) {
#pragma unroll
        for (int rr = 0; rr < 4; ++rr) {
            const unsigned short* rrow = rnb + (size_t)(b0w + m * 16 + kg * 4 + rr) * DD + i0w + r;
#pragma unroll
            for (int n = 0; n < 4; ++n)
                s += acc[m][n][rr] * bf2f(rrow[n * 16]);
        }
    }
#pragma unroll
    for (int off = 1; off < 64; off <<= 1) s += __shfl_xor(s, off);
    __shared__ float sw[4];
    if (lane == 0) sw[wid] = s;
    __syncthreads();
    if (tid == 0) gpart[blockIdx.x] = sw[0] + sw[1] + sw[2] + sw[3];
}

__global__ __launch_bounds__(256) void finalize(const float* __restrict__ gpart,
                                                const float* __restrict__ er,
                                                const float* __restrict__ ea,
                                                const float* __restrict__ temp,
                                                float* __restrict__ out) {
    __shared__ float sb[4][3];
    float s = 0.f, se = 0.f, sa = 0.f;
    for (int i = threadIdx.x; i < 1024; i += 256) s += gpart[i];
    for (int i = threadIdx.x; i < 2048; i += 256) { se += er[i]; sa += ea[i]; }
#pragma unroll
    for (int off = 1; off < 64; off <<= 1) {
        s += __shfl_xor(s, off);
        se += __shfl_xor(se, off);
        sa += __shfl_xor(sa, off);
    }
    int wid = threadIdx.x >> 6, lane = threadIdx.x & 63;
    if (lane == 0) { sb[wid][0] = s; sb[wid][1] = se; sb[wid][2] = sa; }
    __syncthreads();
    if (threadIdx.x == 0) {
        float total = sb[0][0] + sb[1][0] + sb[2][0] + sb[3][0];
        float ser = sb[0][1] + sb[1][1] + sb[2][1] + sb[3][1];
        float sea = sb[0][2] + sb[1][2] + sb[2][2] + sb[3][2];
        float ent_rna = -ser / (float)BD;
        float ent_atac = -sea / (float)BD;
        float avg = 0.5f * (ent_rna + ent_atac);
        float t = temp[0];
        float sg = 1.0f / (1.0f + __expf(-t));
        float scale = sg * 0.1f + (1.0f - sg) * avg;
        float tau = fminf(fmaxf(scale, 0.01f), 1.0f);
        out[0] = -(total / (float)BD) / tau;
    }
}

extern "C" void kernel_launch(void* const* d_in, const int* in_sizes, int n_in,
                              void* d_out, int out_size, void* d_ws, size_t ws_size,
                              hipStream_t stream) {
    const float* z_rna = (const float*)d_in[0];
    const float* z_atac = (const float*)d_in[1];
    const float* link = (const float*)d_in[2];
    const float* temp = (const float*)d_in[3];
    float* out = (float*)d_out;

    char* ws = (char*)d_ws;
    float* gpart = (float*)ws;                          // 1024 f32
    float* er_part = (float*)(ws + 4096);               // 2048 f32
    float* ea_part = (float*)(ws + 12288);              // 2048 f32
    unsigned short* linkb = (unsigned short*)(ws + 32768);                       // 2 MB
    unsigned short* rnb = (unsigned short*)(ws + 32768 + 2097152);               // 16 MB
    unsigned short* anb = (unsigned short*)(ws + 32768 + 2097152 + 16777216);    // 16 MB

    // No memset needed: every partial slot is written unconditionally.
    norm_all<<<4352, 256, 0, stream>>>(z_rna, z_atac, link, rnb, anb, linkb, er_part, ea_part);
    gemm_cos<<<1024, 256, 0, stream>>>(anb, linkb, rnb, gpart);
    finalize<<<1, 256, 0, stream>>>(gpart, er_part, ea_part, temp, out);
}